// Round 2
// baseline (215.589 us; speedup 1.0000x reference)
//
#include <hip/hip_runtime.h>
#include <math.h>

#define NTOK 8192
#define HID  4096
#define NEXP 64
#define TOPK 8

constexpr int TOKB = 16;        // tokens per block
constexpr int KC   = 32;        // k per staged chunk (8 float4-quads)
constexpr int KW   = HID / 4;   // 1024 k per wave (4-wave K-split)
constexpr int NCH  = KW / KC;   // 32 chunks
constexpr int RSTRIDE = 2560;   // floats per wave LDS region (2KB h + 8KB w)

// universal LDS slot swizzle: XOR low-3 slot bits with bits 3..5 (involution)
__device__ __forceinline__ int SW(int slot) { return slot ^ ((slot >> 3) & 7); }

__global__ __launch_bounds__(256, 2)
void moe_gate_kernel(const float* __restrict__ Hm, const float* __restrict__ Wm,
                     float* __restrict__ out)
{
    __shared__ float lds[4 * RSTRIDE];

    const int tid  = threadIdx.x;
    const int wave = tid >> 6;
    const int lane = tid & 63;
    const int s    = lane >> 4;     // k-slice within wave (0..3)
    const int p    = lane & 15;     // tile position
    const int tr   = p >> 3;        // token group (0..1) -> tokens tr*8..tr*8+7
    const int ec   = p & 7;         // expert group (0..7) -> experts ec*8..ec*8+7

    float* R  = lds + wave * RSTRIDE;   // h slots: [kq(8)][t(16)] float4
    float* Rw = R + 512;                // w slots: [kq(8)][e(64)] float4

    const int tok0 = blockIdx.x * TOKB;
    const int kw   = wave * KW;

    // ---- staging identities (constant per lane) ----
    const int st_t  = lane & 15;    // token this lane stages
    const int st_kq = lane >> 4;    // kq (and kq+4)
    const int whoff0 = SW(st_kq * 16 + st_t) * 4;
    const int whoff1 = SW((st_kq + 4) * 16 + st_t) * 4;
    int wwoff[8];
#pragma unroll
    for (int r = 0; r < 8; ++r) wwoff[r] = SW(r * 64 + lane) * 4;

    const float* hgp = Hm + (size_t)(tok0 + st_t) * HID + kw + st_kq * 4;
    const float* wgp = Wm + (size_t)lane * HID + kw;

    // ---- prefetch chunk 0 ----
    float4 hpre0 = *(const float4*)(hgp);
    float4 hpre1 = *(const float4*)(hgp + 16);
    float4 wpre[8];
#pragma unroll
    for (int r = 0; r < 8; ++r) wpre[r] = *(const float4*)(wgp + r * 4);

    const int Kh = (2 * s + tr) & 7;   // h-read column permutation (same for both steps)

    float acc[8][8];
#pragma unroll
    for (int i = 0; i < 8; ++i)
#pragma unroll
        for (int j = 0; j < 8; ++j) acc[i][j] = 0.f;

    for (int c = 0; c < NCH; ++c) {
        // ---- write staged chunk (swizzled b128, conflict-free) ----
        *(float4*)&R[whoff0] = hpre0;
        *(float4*)&R[whoff1] = hpre1;
#pragma unroll
        for (int r = 0; r < 8; ++r) *(float4*)&Rw[wwoff[r]] = wpre[r];

        // ---- prefetch next chunk into regs (wraps harmlessly) ----
        const int cn = (c + 1 == NCH) ? 0 : c + 1;
        {
            const float* hg = hgp + cn * KC;
            hpre0 = *(const float4*)hg;
            hpre1 = *(const float4*)(hg + 16);
            const float* wg = wgp + cn * KC;
#pragma unroll
            for (int r = 0; r < 8; ++r) wpre[r] = *(const float4*)(wg + r * 4);
        }

        // ---- compute: 2 kq-steps (this lane's k-slice), 256 FMA each ----
#pragma unroll
        for (int step = 0; step < 2; ++step) {
            const int kq = s + step * 4;
            const int hb = (kq * 16 + tr * 8) * 4;
            const int wb = (kq * 64 + ec * 8) * 4;
            float4 hq[8], wq[8];
#pragma unroll
            for (int i = 0; i < 8; ++i) hq[i] = *(const float4*)&R[hb + ((i ^ Kh) << 2)];
#pragma unroll
            for (int j = 0; j < 8; ++j) wq[j] = *(const float4*)&Rw[wb + ((j ^ ec) << 2)];
#pragma unroll
            for (int i = 0; i < 8; ++i)
#pragma unroll
                for (int j = 0; j < 8; ++j) {
                    acc[i][j] = fmaf(hq[i].x, wq[j].x, acc[i][j]);
                    acc[i][j] = fmaf(hq[i].y, wq[j].y, acc[i][j]);
                    acc[i][j] = fmaf(hq[i].z, wq[j].z, acc[i][j]);
                    acc[i][j] = fmaf(hq[i].w, wq[j].w, acc[i][j]);
                }
        }
    }

    // ---- reduce the 4 k-slices (lanes p, p+16, p+32, p+48 hold same tile) ----
#pragma unroll
    for (int i = 0; i < 8; ++i)
#pragma unroll
        for (int j = 0; j < 8; ++j) {
            float v = acc[i][j];
            v += __shfl_xor(v, 16);
            v += __shfl_xor(v, 32);
            acc[i][j] = v;
        }

    // slice 0 writes the wave's 16x64 partial over its own (dead) staging region
    if (lane < 16) {
#pragma unroll
        for (int i = 0; i < 8; ++i)
#pragma unroll
            for (int jq = 0; jq < 2; ++jq) {
                float4 v = make_float4(acc[i][jq * 4 + 0], acc[i][jq * 4 + 1],
                                       acc[i][jq * 4 + 2], acc[i][jq * 4 + 3]);
                *(float4*)&R[(tr * 8 + i) * 64 + ec * 8 + jq * 4] = v;
            }
    }
    __syncthreads();

    // ---- softmax + top-8 : lane = expert, each wave handles 4 tokens ----
    float* outw = out;
    float* outi = out + (size_t)NTOK * TOPK;

    for (int t = 0; t < 4; ++t) {
        const int tokL = wave * 4 + t;
        float logit = lds[0 * RSTRIDE + tokL * 64 + lane]
                    + lds[1 * RSTRIDE + tokL * 64 + lane]
                    + lds[2 * RSTRIDE + tokL * 64 + lane]
                    + lds[3 * RSTRIDE + tokL * 64 + lane];

        float m = logit;
#pragma unroll
        for (int off = 32; off; off >>= 1) m = fmaxf(m, __shfl_xor(m, off));
        const float pv = expf(logit - m);
        float ssum = pv;
#pragma unroll
        for (int off = 32; off; off >>= 1) ssum += __shfl_xor(ssum, off);
        float v = pv / ssum;

        const size_t tok = (size_t)(tok0 + tokL);
#pragma unroll
        for (int kk = 0; kk < TOPK; ++kk) {
            float bv = v;
            int   bi = lane;
#pragma unroll
            for (int off = 32; off; off >>= 1) {
                const float ov = __shfl_xor(bv, off);
                const int   oi = __shfl_xor(bi, off);
                if (ov > bv || (ov == bv && oi < bi)) { bv = ov; bi = oi; }
            }
            if (lane == kk) {
                outw[tok * TOPK + kk] = bv;
                outi[tok * TOPK + kk] = (float)bi;
            }
            if (lane == bi) v = -INFINITY;
        }
    }
}

extern "C" void kernel_launch(void* const* d_in, const int* in_sizes, int n_in,
                              void* d_out, int out_size, void* d_ws, size_t ws_size,
                              hipStream_t stream) {
    const float* h = (const float*)d_in[0];   // [8192, 4096] fp32
    const float* w = (const float*)d_in[1];   // [64, 4096] fp32
    float* out = (float*)d_out;               // topk_weight (65536 f32) ++ topk_idx (65536 as float)

    moe_gate_kernel<<<NTOK / TOKB, 256, 0, stream>>>(h, w, out);
}